// Round 14
// baseline (146.409 us; speedup 1.0000x reference)
//
#include <hip/hip_runtime.h>

typedef __attribute__((ext_vector_type(8))) short short8;   // 8 bf16 (MFMA A/B frag)
typedef __attribute__((ext_vector_type(4))) float f32x4;

#define SDIM 32
#define HDIM 34
#define NEXP 12
#define ACOL 256
#define SPB  64            // states per block (image fits LDS)
#define MAXROWS 256        // padded rows <= 64 + 12*15 = 244

// fp32 -> bf16 (round-to-nearest-ish), pack two into one dword
__device__ __forceinline__ unsigned int bpack(float lo, float hi) {
    unsigned int a = __builtin_bit_cast(unsigned int, lo);
    unsigned int b = __builtin_bit_cast(unsigned int, hi);
    return ((a + 0x8000u) >> 16) | ((b + 0x8000u) & 0xffff0000u);
}

// ---- k0: pack Wout into fragment-ordered bf16 + {k32k33 | bias} records ----
// wpack[((e*4+strip)*4+j)*64 + lane] = W[col=strip*64+j*16+(lane&15)][k=8g..8g+7]
// w2b[e*256+col] = { bf16(W[32],W[33]), bf16(bias, 0) }
__global__ __launch_bounds__(256) void k0_wpack(
    const float* __restrict__ Wout, const float* __restrict__ bout,
    uint4* __restrict__ wpack, uint2* __restrict__ w2b)
{
    const int tid = blockIdx.x * 256 + threadIdx.x;
    if (tid < NEXP * 4 * 4 * 64) {
        const int lane = tid & 63;
        const int j    = (tid >> 6) & 3;
        const int stp  = (tid >> 8) & 3;
        const int e    = tid >> 10;
        const int r = lane & 15, g = lane >> 4;
        const int col = stp * 64 + j * 16 + r;
        const float* wr = Wout + ((size_t)e * ACOL + col) * HDIM;
        uint4 q;
        q.x = bpack(wr[g*8+0], wr[g*8+1]);
        q.y = bpack(wr[g*8+2], wr[g*8+3]);
        q.z = bpack(wr[g*8+4], wr[g*8+5]);
        q.w = bpack(wr[g*8+6], wr[g*8+7]);
        wpack[tid] = q;
    }
    if (tid < NEXP * ACOL) {
        const float* wr2 = Wout + (size_t)tid * HDIM;
        w2b[tid] = make_uint2(bpack(wr2[32], wr2[33]), bpack(bout[tid], 0.0f));
    }
}

__global__ __launch_bounds__(256, 3) void actor_kernel(
    const float* __restrict__ states,
    const int*   __restrict__ epoch_idx,
    const float* __restrict__ W1,
    const float* __restrict__ b1,
    const uint4* __restrict__ wpack,
    const uint2* __restrict__ w2b,
    const int*   __restrict__ mask,
    float*       __restrict__ out,
    int nB)
{
    // img: bf16 result image [64 rows (natural order)][256 cols], 512B/row,
    //      8B chunks XOR-swizzled by (row&15) within each 16-chunk strip.
    __shared__ __align__(16) unsigned short img[SPB * ACOL];   // 32768 B
    // xs: 64 B/row bf16 x k0..31, 16B chunks swizzled by ((row>>2)&3).
    __shared__ __align__(16) unsigned int xs[MAXROWS * 16];    // 16384 B
    __shared__ uint2          xt2[MAXROWS];                    // 2048 B {x32x33, 1|0}
    __shared__ unsigned short rowid[MAXROWS];                  // 512 B
    __shared__ int cnt[NEXP], goff[NEXP], ntl[NEXP];
    // total ~51.9 KB -> 3 blocks/CU (12 waves)

    float* w1s = (float*)img;            // aliased: phases 0-2 only (4488 B)
    float* b1s = w1s + HDIM * SDIM;

    const int t    = threadIdx.x;
    const int lane = t & 63;
    const int wv   = t >> 6;
    const int s0   = blockIdx.x * SPB;

    // ---- phase 0: stage W1/b1, zero meta; per-wave mask ballots ----
    for (int i = t; i < HDIM * SDIM; i += 256) w1s[i] = W1[i];
    if (t < HDIM) b1s[t] = b1[t];
    if (t < NEXP) cnt[t] = 0;
    for (int i = t; i < MAXROWS; i += 256) rowid[i] = 0xFFFFu;

    unsigned long long bal0 = __ballot(mask[0 * 64 + lane] != 0);
    unsigned long long bal1 = __ballot(mask[1 * 64 + lane] != 0);
    unsigned long long bal2 = __ballot(mask[2 * 64 + lane] != 0);
    unsigned long long bal3 = __ballot(mask[3 * 64 + lane] != 0);
    const unsigned long long bw =
        (lane < 16) ? bal0 : (lane < 32) ? bal1 : (lane < 48) ? bal2 : bal3;

    const int  sidx  = s0 + t;
    const bool valid = (t < SPB) && (sidx < nB);
    float sr[SDIM];
    int e = 0;
    if (valid) {
        const f32x4* sp = (const f32x4*)(states + (size_t)sidx * SDIM);
        #pragma unroll
        for (int q = 0; q < SDIM / 4; ++q) {
            f32x4 v = sp[q];
            sr[4*q+0] = v[0]; sr[4*q+1] = v[1]; sr[4*q+2] = v[2]; sr[4*q+3] = v[3];
        }
        e = epoch_idx[sidx];
    }
    __syncthreads();                 // cnt zeroed, w1s staged

    int rank = 0;
    if (valid) rank = atomicAdd(&cnt[e], 1);
    __syncthreads();                 // cnt final

    if (t == 0) {
        int base = 0;
        #pragma unroll
        for (int i = 0; i < NEXP; ++i) {
            goff[i] = base;
            int nt = (cnt[i] + 15) >> 4;
            ntl[i] = nt;
            base += nt << 4;
        }
    }
    float x[HDIM];
    if (valid) {
        #pragma unroll 2
        for (int h = 0; h < HDIM; ++h) {
            float acc = b1s[h];
            const float4* wr = (const float4*)(w1s + h * SDIM);
            #pragma unroll
            for (int q = 0; q < SDIM / 4; ++q) {
                float4 wv4 = wr[q];
                acc = fmaf(sr[4*q+0], wv4.x, acc);
                acc = fmaf(sr[4*q+1], wv4.y, acc);
                acc = fmaf(sr[4*q+2], wv4.z, acc);
                acc = fmaf(sr[4*q+3], wv4.w, acc);
            }
            x[h] = fmaxf(acc, 0.0f);
        }
    }
    __syncthreads();                 // goff/ntl ready; w1s reads done

    // ---- phase 2: scatter bf16 x row into sorted+padded slot (swizzled) ----
    if (valid) {
        const int slot = goff[e] + rank;
        const unsigned sw = (((unsigned)slot >> 2) & 3u) << 4;
        char* rbase = (char*)xs + slot * 64;
        unsigned d[17];
        #pragma unroll
        for (int k = 0; k < 17; ++k) d[k] = bpack(x[2*k], x[2*k+1]);
        #pragma unroll
        for (int c = 0; c < 4; ++c) {
            f32x4 q;
            q[0] = __builtin_bit_cast(float, d[4*c+0]);
            q[1] = __builtin_bit_cast(float, d[4*c+1]);
            q[2] = __builtin_bit_cast(float, d[4*c+2]);
            q[3] = __builtin_bit_cast(float, d[4*c+3]);
            *(f32x4*)(rbase + (((unsigned)(c * 16)) ^ sw)) = q;
        }
        xt2[slot]   = make_uint2(d[16], bpack(1.0f, 0.0f));  // {x32,x33} | {1,0}
        rowid[slot] = (unsigned short)t;
    }
    __syncthreads();                 // xs/xt2/rowid visible

    // ---- phase 3: barrier-free swapped-operand MFMA into natural-row image ----
    const int r = lane & 15;         // A action row / B state col within tile
    const int g = lane >> 4;         // k-group
    const short8 z8 = __builtin_bit_cast(short8, make_uint4(0u, 0u, 0u, 0u));

    for (int e2 = 0; e2 < NEXP; ++e2) {
        const int ntiles = ntl[e2];
        if (ntiles == 0) continue;

        short8 wf[4], wx[4];
        const uint4* wp = wpack + ((size_t)(e2 * 4 + wv) * 4) * 64 + lane;
        #pragma unroll
        for (int j = 0; j < 4; ++j) {
            wf[j] = __builtin_bit_cast(short8, wp[j * 64]);
            uint2 we = make_uint2(0u, 0u);
            if (g == 0) we = w2b[e2 * ACOL + wv * 64 + j * 16 + r];
            wx[j] = __builtin_bit_cast(short8, make_uint4(we.x, we.y, 0u, 0u));
        }

        const int tb = goff[e2];
        for (int st = 0; st < ntiles; ++st) {
            const int row = tb + (st << 4) + r;
            const char* rp = (const char*)xs + row * 64;
            short8 bx = *(const short8*)(rp +
                          (((unsigned)(g * 16)) ^ ((((unsigned)row >> 2) & 3u) << 4)));
            const uint2 x2 = xt2[row];
            const short8 bxe = (g == 0)
                ? __builtin_bit_cast(short8, make_uint4(x2.x, x2.y, 0u, 0u)) : z8;
            const unsigned rid = rowid[row];

            #pragma unroll
            for (int j = 0; j < 4; ++j) {
                f32x4 a = {0.f, 0.f, 0.f, 0.f};
                a = __builtin_amdgcn_mfma_f32_16x16x32_bf16(wf[j], bx,  a, 0, 0, 0);
                a = __builtin_amdgcn_mfma_f32_16x16x32_bf16(wx[j], bxe, a, 0, 0, 0);
                if (rid != 0xFFFFu) {
                    // acc = cols (wv*64 + 16j + 4g .. +3) of natural row rid
                    const unsigned chunk = ((unsigned)wv << 4) |
                        (((unsigned)(4 * j + g)) ^ (rid & 15u));
                    *(uint2*)((char*)img + rid * 512 + chunk * 8) =
                        make_uint2(bpack(a[0], a[1]), bpack(a[2], a[3]));
                }
            }
        }
    }
    __syncthreads();                 // image complete

    // ---- phase 4: natural-order sequential row stores (1KB/instr, ascending) ----
    const float NEG = -1e9f;
    for (int s = wv; s < SPB; s += 4) {
        if (s0 + s >= nB) break;
        const unsigned sl = (unsigned)s & 15u;
        const unsigned lo = ((unsigned)lane & 15u) ^ sl;    // swizzled sub-chunk
        const unsigned ch = ((unsigned)lane & 48u) | lo;    // this lane's 4-col chunk
        const uint2 dv = *(const uint2*)((const char*)img + s * 512 + ch * 8);
        const unsigned nib = (unsigned)(bw >> (4u * lo)) & 15u;
        f32x4 v;
        v[0] = __builtin_bit_cast(float, dv.x << 16);
        v[1] = __builtin_bit_cast(float, dv.x & 0xffff0000u);
        v[2] = __builtin_bit_cast(float, dv.y << 16);
        v[3] = __builtin_bit_cast(float, dv.y & 0xffff0000u);
        v[0] = (nib & 1u) ? v[0] : NEG;
        v[1] = (nib & 2u) ? v[1] : NEG;
        v[2] = (nib & 4u) ? v[2] : NEG;
        v[3] = (nib & 8u) ? v[3] : NEG;
        *(f32x4*)(out + (size_t)(s0 + s) * ACOL + ch * 4) = v;
    }
}

extern "C" void kernel_launch(void* const* d_in, const int* in_sizes, int n_in,
                              void* d_out, int out_size, void* d_ws, size_t ws_size,
                              hipStream_t stream) {
    const float* states    = (const float*)d_in[0];
    const int*   epoch_idx = (const int*)  d_in[1];
    const float* W1        = (const float*)d_in[2];
    const float* b1        = (const float*)d_in[3];
    const float* Wout      = (const float*)d_in[4];
    const float* bout      = (const float*)d_in[5];
    const int*   mask      = (const int*)  d_in[6];
    float*       out       = (float*)d_out;

    const int nB   = in_sizes[0] / SDIM;
    const int grid = (nB + SPB - 1) / SPB;

    uint4* wpack = (uint4*)d_ws;                                // 196608 B
    uint2* w2b   = (uint2*)((char*)d_ws + 196608);              // 24576 B

    k0_wpack<<<48, 256, 0, stream>>>(Wout, bout, wpack, w2b);
    actor_kernel<<<grid, 256, 0, stream>>>(states, epoch_idx, W1, b1,
                                           wpack, w2b, mask, out, nB);
}

// Round 15
// 109.853 us; speedup vs baseline: 1.3328x; 1.3328x over previous
//
#include <hip/hip_runtime.h>

typedef __attribute__((ext_vector_type(8))) short short8;   // 8 bf16 (MFMA A/B frag)
typedef __attribute__((ext_vector_type(4))) float f32x4;
typedef __attribute__((ext_vector_type(4))) int   i32x4;

#define SDIM 32
#define HDIM 34
#define NEXP 12
#define ACOL 256
#define SPB  256
#define MAXROWS 448        // max padded rows = 256 + 12*15 = 436
#define SLABS 260          // per-wave slab stride in shorts (16 rows x 260)

// fp32 -> bf16 (round-to-nearest-ish), pack two into one dword
__device__ __forceinline__ unsigned int bpack(float lo, float hi) {
    unsigned int a = __builtin_bit_cast(unsigned int, lo);
    unsigned int b = __builtin_bit_cast(unsigned int, hi);
    return ((a + 0x8000u) >> 16) | ((b + 0x8000u) & 0xffff0000u);
}

// ---- k0: pack Wout fragment-ordered + {k32k33 | bias} records ----
// wpack[(e*16+j)*64 + lane] = 8 bf16 of W[col=16j+(lane&15)][k=8g..8g+7], g=lane>>4
// w2b[e*256+col] = { bf16(W[32],W[33]), bf16(bias, 0) }
__global__ __launch_bounds__(256) void k0_wpack(
    const float* __restrict__ Wout, const float* __restrict__ bout,
    uint4* __restrict__ wpack, uint2* __restrict__ w2b)
{
    const int tid = blockIdx.x * 256 + threadIdx.x;
    if (tid < NEXP * 16 * 64) {
        const int lane = tid & 63;
        const int j    = (tid >> 6) & 15;
        const int e    = tid >> 10;
        const int r = lane & 15, g = lane >> 4;
        const int col = j * 16 + r;
        const float* wr = Wout + ((size_t)e * ACOL + col) * HDIM;
        uint4 q;
        q.x = bpack(wr[g*8+0], wr[g*8+1]);
        q.y = bpack(wr[g*8+2], wr[g*8+3]);
        q.z = bpack(wr[g*8+4], wr[g*8+5]);
        q.w = bpack(wr[g*8+6], wr[g*8+7]);
        wpack[tid] = q;
    }
    if (tid < NEXP * ACOL) {
        const float* wr2 = Wout + (size_t)tid * HDIM;
        w2b[tid] = make_uint2(bpack(wr2[32], wr2[33]), bpack(bout[tid], 0.0f));
    }
}

__global__ __launch_bounds__(256, 2) void actor_kernel(
    const float* __restrict__ states,
    const int*   __restrict__ epoch_idx,
    const float* __restrict__ W1,
    const float* __restrict__ b1,
    const uint4* __restrict__ wpack,
    const uint2* __restrict__ w2b,
    const int*   __restrict__ mask,
    float*       __restrict__ out,
    int nB)
{
    // xs: 64 B/row = bf16 k0..31 in 4 16B chunks, chunk c at (c ^ ((row>>2)&3)).
    __shared__ __align__(16) unsigned int xs[MAXROWS * 16];      // 28672 B
    __shared__ uint2          xt2[MAXROWS];                      // 3584 B {x32x33, 1|0}
    __shared__ unsigned short lrid[MAXROWS];                     // 896 B
    __shared__ __align__(8) unsigned short slab[4][16 * SLABS];  // 33280 B private
    __shared__ int texp[32];
    __shared__ int cnt[NEXP], goff[NEXP], ntl[NEXP], ntt;
    // total ~66.8 KB -> 2 blocks/CU

    float* w1s = (float*)&slab[0][0];    // aliased: phases 0-1 only (4488 B)
    float* b1s = w1s + HDIM * SDIM;

    const int t  = threadIdx.x;
    const int s0 = blockIdx.x * SPB;

    // ---- phase 0 ----
    for (int i = t; i < HDIM * SDIM; i += 256) w1s[i] = W1[i];
    if (t < HDIM) b1s[t] = b1[t];
    if (t < NEXP) cnt[t] = 0;
    for (int i = t; i < MAXROWS; i += 256) lrid[i] = 0xFFFFu;

    const int  sidx  = s0 + t;
    const bool valid = (sidx < nB);
    float sr[SDIM];
    int e = 0;
    if (valid) {
        const f32x4* sp = (const f32x4*)(states + (size_t)sidx * SDIM);
        #pragma unroll
        for (int q = 0; q < SDIM / 4; ++q) {
            f32x4 v = sp[q];
            sr[4*q+0] = v[0]; sr[4*q+1] = v[1]; sr[4*q+2] = v[2]; sr[4*q+3] = v[3];
        }
        e = epoch_idx[sidx];
    }
    __syncthreads();                 // cnt zeroed, w1s staged

    int rank = 0;
    if (valid) rank = atomicAdd(&cnt[e], 1);
    __syncthreads();                 // cnt final

    if (t == 0) {
        int base = 0;
        #pragma unroll
        for (int i = 0; i < NEXP; ++i) {
            goff[i] = base;
            int nt = (cnt[i] + 15) >> 4;
            ntl[i] = nt;
            base += nt << 4;
        }
        ntt = base >> 4;
    }
    float x[HDIM];
    if (valid) {
        #pragma unroll 2
        for (int h = 0; h < HDIM; ++h) {
            float acc = b1s[h];
            const float4* wr = (const float4*)(w1s + h * SDIM);
            #pragma unroll
            for (int q = 0; q < SDIM / 4; ++q) {
                float4 wv4 = wr[q];
                acc = fmaf(sr[4*q+0], wv4.x, acc);
                acc = fmaf(sr[4*q+1], wv4.y, acc);
                acc = fmaf(sr[4*q+2], wv4.z, acc);
                acc = fmaf(sr[4*q+3], wv4.w, acc);
            }
            x[h] = fmaxf(acc, 0.0f);
        }
    }
    __syncthreads();                 // goff/ntl/ntt ready; w1s reads done

    if (t < NEXP) {                  // tile -> expert map
        const int tb0 = goff[t] >> 4;
        for (int k = 0; k < ntl[t]; ++k) texp[tb0 + k] = t;
    }
    // ---- phase 2: scatter bf16 x row into sorted+padded slot (swizzled) ----
    if (valid) {
        const int slot = goff[e] + rank;
        const unsigned sw = (((unsigned)slot >> 2) & 3u) << 4;
        char* rbase = (char*)xs + slot * 64;
        unsigned d[17];
        #pragma unroll
        for (int k = 0; k < 17; ++k) d[k] = bpack(x[2*k], x[2*k+1]);
        #pragma unroll
        for (int c = 0; c < 4; ++c) {
            f32x4 q;
            q[0] = __builtin_bit_cast(float, d[4*c+0]);
            q[1] = __builtin_bit_cast(float, d[4*c+1]);
            q[2] = __builtin_bit_cast(float, d[4*c+2]);
            q[3] = __builtin_bit_cast(float, d[4*c+3]);
            *(f32x4*)(rbase + (((unsigned)(c * 16)) ^ sw)) = q;
        }
        xt2[slot]  = make_uint2(d[16], bpack(1.0f, 0.0f));   // {x32,x33} | {1,0}
        lrid[slot] = (unsigned short)t;
    }
    __syncthreads();                 // xs/xt2/lrid/texp visible — LAST barrier

    // ---- phase 3: wave-private tiles, swapped-operand MFMA, zero barriers ----
    const int wv   = t >> 6;
    const int lane = t & 63;
    const int s    = lane & 15;      // state row within tile (B col, A row sel)
    const int g    = lane >> 4;      // k-group
    const float NEG = -1e9f;
    const i32x4 mq = *(const i32x4*)(mask + 4 * lane);
    const short8 z8 = __builtin_bit_cast(short8, make_uint4(0u, 0u, 0u, 0u));
    unsigned short* myslab = slab[wv];
    float* outb = out + (size_t)s0 * ACOL;

    const int nt_tot = ntt;
    for (int tile = wv; tile < nt_tot; tile += 4) {
        const int e2 = texp[tile];
        const int rb = tile << 4;
        const int row = rb + s;

        // B fragments: x row (this lane's state), k0..31 + ext {x32,x33,1}
        const char* rp = (const char*)xs + row * 64;
        short8 bx = *(const short8*)(rp +
                      (((unsigned)(g * 16)) ^ ((((unsigned)row >> 2) & 3u) << 4)));
        const uint2 x2 = xt2[row];
        const short8 bxe = (g == 0)
            ? __builtin_bit_cast(short8, make_uint4(x2.x, x2.y, 0u, 0u)) : z8;

        const uint4* wp = wpack + (size_t)(e2 * 16) * 64 + lane;
        const uint2* wb = w2b + e2 * ACOL + s;

        // compute all 16 col-tiles; lane -> 4 consecutive cols of state row
        #pragma unroll
        for (int j = 0; j < 16; ++j) {
            const uint4 f = wp[j * 64];
            uint2 we = make_uint2(0u, 0u);
            if (g == 0) we = wb[j * 16];
            const short8 aext = __builtin_bit_cast(short8,
                                  make_uint4(we.x, we.y, 0u, 0u));
            f32x4 a = {0.f, 0.f, 0.f, 0.f};
            a = __builtin_amdgcn_mfma_f32_16x16x32_bf16(
                    __builtin_bit_cast(short8, f), bx, a, 0, 0, 0);
            a = __builtin_amdgcn_mfma_f32_16x16x32_bf16(aext, bxe, a, 0, 0, 0);
            // cols 16j+4g..+3 of state row s -> one packed b64 write
            *(uint2*)(myslab + s * SLABS + 16 * j + 4 * g) =
                make_uint2(bpack(a[0], a[1]), bpack(a[2], a[3]));
        }

        // stream 16 full 1KB rows (intra-wave ordering only; deep store burst)
        #pragma unroll
        for (int lrow = 0; lrow < 16; ++lrow) {
            const unsigned rid = lrid[rb + lrow];
            const uint2 dv = *(const uint2*)(myslab + lrow * SLABS + 4 * lane);
            f32x4 v;
            v[0] = __builtin_bit_cast(float, dv.x << 16);
            v[1] = __builtin_bit_cast(float, dv.x & 0xffff0000u);
            v[2] = __builtin_bit_cast(float, dv.y << 16);
            v[3] = __builtin_bit_cast(float, dv.y & 0xffff0000u);
            v[0] = mq[0] ? v[0] : NEG;
            v[1] = mq[1] ? v[1] : NEG;
            v[2] = mq[2] ? v[2] : NEG;
            v[3] = mq[3] ? v[3] : NEG;
            if (rid != 0xFFFFu)
                *(f32x4*)(outb + (size_t)rid * ACOL + 4 * lane) = v;
        }
    }
}

extern "C" void kernel_launch(void* const* d_in, const int* in_sizes, int n_in,
                              void* d_out, int out_size, void* d_ws, size_t ws_size,
                              hipStream_t stream) {
    const float* states    = (const float*)d_in[0];
    const int*   epoch_idx = (const int*)  d_in[1];
    const float* W1        = (const float*)d_in[2];
    const float* b1        = (const float*)d_in[3];
    const float* Wout      = (const float*)d_in[4];
    const float* bout      = (const float*)d_in[5];
    const int*   mask      = (const int*)  d_in[6];
    float*       out       = (float*)d_out;

    const int nB   = in_sizes[0] / SDIM;
    const int grid = (nB + SPB - 1) / SPB;

    uint4* wpack = (uint4*)d_ws;                                // 196608 B
    uint2* w2b   = (uint2*)((char*)d_ws + 196608);              // 24576 B

    k0_wpack<<<48, 256, 0, stream>>>(Wout, bout, wpack, w2b);
    actor_kernel<<<grid, 256, 0, stream>>>(states, epoch_idx, W1, b1,
                                           wpack, w2b, mask, out, nB);
}